// Round 1
// baseline (36.780 us; speedup 1.0000x reference)
//
#include <hip/hip_runtime.h>

#define SLEN   300
#define PT     20
#define STEP   4
#define EPAD   2
#define MAXD   2
#define NBANDS 2
#define NS     30
#define NGAL   8
#define BATCH  8
#define N1     71            // (300-20)/4+1
#define NPT    (N1*N1)       // 5041
#define NSUB   (BATCH*NPT)   // 40328

// ---- output layout (flat float32, in reference return order) ----
// [0]                image_ptiles : NSUB*NBANDS*PT*PT = 32,262,400
// [32,262,400]       tile_locs    : NSUB*MAXD*2       =    161,312
// [32,423,712]       tile_gal     : NSUB*MAXD*NGAL    =    645,248
// [33,068,960]       tile_flux    : NSUB*MAXD*NBANDS  =    161,312
// [33,230,272]       tile_n_src   : NSUB              =     40,328
// [33,270,600]       tile_is_on   : NSUB*MAXD         =     80,656
// total = 33,351,256

#define OFF_LOCS 32262400
#define OFF_GAL  32423712
#define OFF_FLUX 33068960
#define OFF_N    33230272
#define OFF_ISON 33270600

// Kernel 1: patch extraction. One thread = one float4 (4 contiguous pixels of
// a patch row). out[((sub*NB + c)*PT + r)*PT + q*4 ..] = img[b,c,i*4+r, j*4+q*4 ..]
// Both sides 16B-aligned (row stride 1200B, col offsets multiples of 16B).
__global__ __launch_bounds__(256) void tile_images_kernel(
    const float* __restrict__ img, float* __restrict__ out)
{
    const int TOT4 = NSUB * NBANDS * PT * (PT / 4);  // 8,065,600
    int v = blockIdx.x * blockDim.x + threadIdx.x;
    if (v >= TOT4) return;

    int q     = v % (PT / 4);        // which float4 within the row (0..4)
    int rest  = v / (PT / 4);
    int r     = rest % PT;           // row within patch
    int rest2 = rest / PT;
    int c     = rest2 % NBANDS;      // band
    int sub   = rest2 / NBANDS;      // 0..NSUB-1
    int b     = sub / NPT;
    int t     = sub % NPT;
    int i     = t / N1;
    int j     = t % N1;

    const float* src = img
        + ((size_t)((b * NBANDS + c) * SLEN + i * STEP + r)) * SLEN
        + j * STEP + q * 4;
    reinterpret_cast<float4*>(out)[v] = *reinterpret_cast<const float4*>(src);
}

// Kernel 2: per-tile catalog. Scan the 30 sources of this batch, keep the
// first <=2 falling strictly inside (tc+1.5, tc+17.5) in both coords
// (the lp != 0 check is subsumed by lp > lo >= 1.5).
__global__ __launch_bounds__(256) void catalog_kernel(
    const float* __restrict__ locs,
    const float* __restrict__ gal,
    const float* __restrict__ flux,
    float* __restrict__ out)
{
    int sub = blockIdx.x * blockDim.x + threadIdx.x;
    if (sub >= NSUB) return;

    int b = sub / NPT;
    int t = sub % NPT;
    int i = t / N1;
    int j = t % N1;

    const float lox = (float)(i * STEP) + 1.5f;   // tc.x + EP - 0.5
    const float loy = (float)(j * STEP) + 1.5f;
    const float hix = lox + 16.0f;                // tc - 0.5 + PT - EP
    const float hiy = loy + 16.0f;

    int   cnt = 0;
    int   sid[2] = {0, 0};
    float slx[2] = {0.f, 0.f};
    float sly[2] = {0.f, 0.f};

    const float* lb = locs + (size_t)b * NS * 2;
    #pragma unroll
    for (int s = 0; s < NS; ++s) {
        float lx = lb[2 * s + 0] * (float)(SLEN - 1);
        float ly = lb[2 * s + 1] * (float)(SLEN - 1);
        bool on = (lx > lox) && (lx < hix) && (ly > loy) && (ly < hiy);
        if (on) {
            if (cnt < MAXD) { sid[cnt] = s; slx[cnt] = lx; sly[cnt] = ly; }
            cnt++;
        }
    }

    const float inv_scale = 1.0f / 16.0f;  // 1/(PT - 2*EP), exact in binary

    // tile_locs: (MAXD,2) -> one float4
    float4 lv;
    lv.x = (cnt > 0) ? fmaxf((slx[0] - lox) * inv_scale, 0.0f) : 0.0f;
    lv.y = (cnt > 0) ? fmaxf((sly[0] - loy) * inv_scale, 0.0f) : 0.0f;
    lv.z = (cnt > 1) ? fmaxf((slx[1] - lox) * inv_scale, 0.0f) : 0.0f;
    lv.w = (cnt > 1) ? fmaxf((sly[1] - loy) * inv_scale, 0.0f) : 0.0f;
    reinterpret_cast<float4*>(out + OFF_LOCS)[sub] = lv;

    // tile_gal: (MAXD, NGAL) -> 4 float4
    float4 g0 = {0,0,0,0}, g1 = {0,0,0,0}, g2 = {0,0,0,0}, g3 = {0,0,0,0};
    if (cnt > 0) {
        const float4* gp = reinterpret_cast<const float4*>(
            gal + ((size_t)(b * NS + sid[0])) * NGAL);
        g0 = gp[0]; g1 = gp[1];
    }
    if (cnt > 1) {
        const float4* gp = reinterpret_cast<const float4*>(
            gal + ((size_t)(b * NS + sid[1])) * NGAL);
        g2 = gp[0]; g3 = gp[1];
    }
    float4* go = reinterpret_cast<float4*>(out + OFF_GAL) + (size_t)sub * 4;
    go[0] = g0; go[1] = g1; go[2] = g2; go[3] = g3;

    // tile_flux: (MAXD, NBANDS) -> one float4
    float4 fv = {0,0,0,0};
    if (cnt > 0) {
        const float2 f = reinterpret_cast<const float2*>(
            flux + ((size_t)(b * NS + sid[0])) * NBANDS)[0];
        fv.x = f.x; fv.y = f.y;
    }
    if (cnt > 1) {
        const float2 f = reinterpret_cast<const float2*>(
            flux + ((size_t)(b * NS + sid[1])) * NBANDS)[0];
        fv.z = f.x; fv.w = f.y;
    }
    reinterpret_cast<float4*>(out + OFF_FLUX)[sub] = fv;

    // tile_n_sources (min(cnt,2)) and tile_is_on, written as float values
    out[OFF_N + sub] = (float)(cnt < MAXD ? cnt : MAXD);
    float2 ison;
    ison.x = (cnt > 0) ? 1.0f : 0.0f;
    ison.y = (cnt > 1) ? 1.0f : 0.0f;
    reinterpret_cast<float2*>(out + OFF_ISON)[sub] = ison;
}

extern "C" void kernel_launch(void* const* d_in, const int* in_sizes, int n_in,
                              void* d_out, int out_size, void* d_ws, size_t ws_size,
                              hipStream_t stream)
{
    const float* images = (const float*)d_in[0];
    const float* locs   = (const float*)d_in[1];
    const float* gal    = (const float*)d_in[2];
    const float* flux   = (const float*)d_in[3];
    float* out = (float*)d_out;

    const int TOT4 = NSUB * NBANDS * PT * (PT / 4);          // 8,065,600
    int blocks1 = (TOT4 + 255) / 256;                         // 31,507
    tile_images_kernel<<<blocks1, 256, 0, stream>>>(images, out);

    int blocks2 = (NSUB + 255) / 256;                         // 158
    catalog_kernel<<<blocks2, 256, 0, stream>>>(locs, gal, flux, out);
}

// Round 3
// 32.761 us; speedup vs baseline: 1.1227x; 1.1227x over previous
//
#include <hip/hip_runtime.h>

#define SLEN   300
#define PT     20
#define STEP   4
#define MAXD   2
#define NBANDS 2
#define NS     30
#define NGAL   8
#define BATCH  8
#define N1     71            // (300-20)/4+1
#define NPT    (N1*N1)       // 5041
#define NSUB   (BATCH*NPT)   // 40328

// ---- output layout (flat float32, in reference return order) ----
#define OFF_LOCS 32262400
#define OFF_GAL  32423712
#define OFF_FLUX 33068960
#define OFF_N    33230272
#define OFF_ISON 33270600

// tiling decomposition: one block per (batch, patch-row i, j-quarter)
#define JQ   4
#define NJQ  18                               // j's per quarter (last has 17)
#define TILE_BLOCKS (BATCH * N1 * JQ)         // 2272
#define CAT_BLOCKS  ((NSUB + 255) / 256)      // 158
#define LDSTRIDE 92                           // 88 cols padded to 92 (16B-aligned, bank-skewed)
#define NF4 22                                // float4s per LDS row (88 cols)

typedef float vf4 __attribute__((ext_vector_type(4)));  // native vec: ok for nontemporal builtins

__global__ __launch_bounds__(256) void fused_kernel(
    const float* __restrict__ img,
    const float* __restrict__ locs,
    const float* __restrict__ gal,
    const float* __restrict__ flux,
    float* __restrict__ out)
{
    const int bid = blockIdx.x;
    const int tid = threadIdx.x;

    if (bid < TILE_BLOCKS) {
        // ---------------- patch extraction ----------------
        __shared__ float lds[NBANDS * PT * LDSTRIDE];   // 14,720 B
        const int jq = bid & 3;
        const int bi = bid >> 2;
        const int i  = bi % N1;
        const int b  = bi / N1;
        const int j0 = jq * NJQ;
        const int nj = (jq == 3) ? (N1 - 3 * NJQ) : NJQ;   // 17 or 18
        const int col0 = j0 * STEP;

        // stage image strip: bands x 20 rows x <=88 cols (each row contiguous)
        for (int u = tid; u < NBANDS * PT * NF4; u += 256) {
            int k  = u % NF4;
            int rc = u / NF4;
            int r  = rc % PT;
            int c  = rc / PT;
            int col = col0 + k * 4;
            if (col + 3 < SLEN) {   // skip the 1 out-of-row float4 in the last quarter
                const vf4 v = *reinterpret_cast<const vf4*>(
                    img + ((size_t)((b * NBANDS + c) * SLEN + i * STEP + r)) * SLEN + col);
                *reinterpret_cast<vf4*>(&lds[(c * PT + r) * LDSTRIDE + k * 4]) = v;
            }
        }
        __syncthreads();

        // emit nj patches: output for sub in [sub0, sub0+nj) is one contiguous
        // float4 stream; within-chunk index w == (jj*200 + c*100 + rr*5 + q)
        const int sub0 = b * NPT + i * N1 + j0;
        vf4* dst = reinterpret_cast<vf4*>(out) + (size_t)sub0 * 200;
        const int tot = nj * 200;
        for (int w = tid; w < tot; w += 256) {
            int jj  = w / 200;
            int rem = w % 200;
            int q   = rem % 5;
            int rr  = (rem / 5) % 20;
            int c   = rem / 100;
            const vf4 v = *reinterpret_cast<const vf4*>(
                &lds[(c * PT + rr) * LDSTRIDE + jj * 4 + q * 4]);
            __builtin_nontemporal_store(v, dst + w);
        }
    } else {
        // ---------------- per-tile catalog ----------------
        const int sub = (bid - TILE_BLOCKS) * 256 + tid;
        if (sub >= NSUB) return;

        const int b = sub / NPT;
        const int t = sub % NPT;
        const int i = t / N1;
        const int j = t % N1;

        const float lox = (float)(i * STEP) + 1.5f;   // tc.x + EP - 0.5
        const float loy = (float)(j * STEP) + 1.5f;
        const float hix = lox + 16.0f;                // tc - 0.5 + PT - EP
        const float hiy = loy + 16.0f;

        int   cnt = 0;
        int   sid[2] = {0, 0};
        float slx[2] = {0.f, 0.f};
        float sly[2] = {0.f, 0.f};

        const float* lb = locs + (size_t)b * NS * 2;
        #pragma unroll
        for (int s = 0; s < NS; ++s) {
            float lx = lb[2 * s + 0] * (float)(SLEN - 1);
            float ly = lb[2 * s + 1] * (float)(SLEN - 1);
            bool on = (lx > lox) && (lx < hix) && (ly > loy) && (ly < hiy);
            if (on) {
                if (cnt < MAXD) { sid[cnt] = s; slx[cnt] = lx; sly[cnt] = ly; }
                cnt++;
            }
        }

        const float inv_scale = 1.0f / 16.0f;  // 1/(PT-2*EP), exact

        float4 lv;
        lv.x = (cnt > 0) ? fmaxf((slx[0] - lox) * inv_scale, 0.0f) : 0.0f;
        lv.y = (cnt > 0) ? fmaxf((sly[0] - loy) * inv_scale, 0.0f) : 0.0f;
        lv.z = (cnt > 1) ? fmaxf((slx[1] - lox) * inv_scale, 0.0f) : 0.0f;
        lv.w = (cnt > 1) ? fmaxf((sly[1] - loy) * inv_scale, 0.0f) : 0.0f;
        reinterpret_cast<float4*>(out + OFF_LOCS)[sub] = lv;

        float4 g0 = {0,0,0,0}, g1 = {0,0,0,0}, g2 = {0,0,0,0}, g3 = {0,0,0,0};
        if (cnt > 0) {
            const float4* gp = reinterpret_cast<const float4*>(
                gal + ((size_t)(b * NS + sid[0])) * NGAL);
            g0 = gp[0]; g1 = gp[1];
        }
        if (cnt > 1) {
            const float4* gp = reinterpret_cast<const float4*>(
                gal + ((size_t)(b * NS + sid[1])) * NGAL);
            g2 = gp[0]; g3 = gp[1];
        }
        float4* go = reinterpret_cast<float4*>(out + OFF_GAL) + (size_t)sub * 4;
        go[0] = g0; go[1] = g1; go[2] = g2; go[3] = g3;

        float4 fv = {0,0,0,0};
        if (cnt > 0) {
            const float2 f = reinterpret_cast<const float2*>(
                flux + ((size_t)(b * NS + sid[0])) * NBANDS)[0];
            fv.x = f.x; fv.y = f.y;
        }
        if (cnt > 1) {
            const float2 f = reinterpret_cast<const float2*>(
                flux + ((size_t)(b * NS + sid[1])) * NBANDS)[0];
            fv.z = f.x; fv.w = f.y;
        }
        reinterpret_cast<float4*>(out + OFF_FLUX)[sub] = fv;

        out[OFF_N + sub] = (float)(cnt < MAXD ? cnt : MAXD);
        float2 ison;
        ison.x = (cnt > 0) ? 1.0f : 0.0f;
        ison.y = (cnt > 1) ? 1.0f : 0.0f;
        reinterpret_cast<float2*>(out + OFF_ISON)[sub] = ison;
    }
}

extern "C" void kernel_launch(void* const* d_in, const int* in_sizes, int n_in,
                              void* d_out, int out_size, void* d_ws, size_t ws_size,
                              hipStream_t stream)
{
    const float* images = (const float*)d_in[0];
    const float* locs   = (const float*)d_in[1];
    const float* gal    = (const float*)d_in[2];
    const float* flux   = (const float*)d_in[3];
    float* out = (float*)d_out;

    fused_kernel<<<TILE_BLOCKS + CAT_BLOCKS, 256, 0, stream>>>(
        images, locs, gal, flux, out);
}

// Round 4
// 29.992 us; speedup vs baseline: 1.2263x; 1.0923x over previous
//
#include <hip/hip_runtime.h>

#define SLEN   300
#define PT     20
#define STEP   4
#define MAXD   2
#define NBANDS 2
#define NS     30
#define NGAL   8
#define BATCH  8
#define N1     71            // (300-20)/4+1
#define NPT    (N1*N1)       // 5041
#define NSUB   (BATCH*NPT)   // 40328

// ---- output layout (flat float32, in reference return order) ----
#define OFF_LOCS 32262400
#define OFF_GAL  32423712
#define OFF_FLUX 33068960
#define OFF_N    33230272
#define OFF_ISON 33270600

// tiling decomposition: one block per (batch, patch-row i, j-quarter)
#define JQ   4
#define NJQ  18                               // j's per quarter (last has 17)
#define TILE_BLOCKS (BATCH * N1 * JQ)         // 2272
#define CAT_BLOCKS  ((NSUB + 255) / 256)      // 158

typedef float vf4 __attribute__((ext_vector_type(4)));

// No LDS, no __syncthreads: the per-block image strip (2 bands x 20 rows x
// <=88 cols = 14.7 KB) fits in L1 (32 KB), so the emit loop reads straight
// from global. Reads per 5-lane group are 80B contiguous (coalesced); stores
// are a perfectly linear per-block float4 stream (1KB per wave-store, 128B
// aligned). Plain stores (the 7.1 TB/s memset path), not nontemporal.
__global__ __launch_bounds__(256) void fused_kernel(
    const float* __restrict__ img,
    const float* __restrict__ locs,
    const float* __restrict__ gal,
    const float* __restrict__ flux,
    float* __restrict__ out)
{
    const int bid = blockIdx.x;
    const int tid = threadIdx.x;

    if (bid < TILE_BLOCKS) {
        // ---------------- patch extraction (direct L1-cached reads) --------
        const int jq = bid & 3;
        const int bi = bid >> 2;
        const int i  = bi % N1;
        const int b  = bi / N1;
        const int j0 = jq * NJQ;
        const int nj = (jq == 3) ? (N1 - 3 * NJQ) : NJQ;   // 17 or 18
        const int col0 = j0 * STEP;
        const int i4   = i * STEP;

        const int sub0 = b * NPT + i * N1 + j0;
        vf4* dst = reinterpret_cast<vf4*>(out) + (size_t)sub0 * 200;
        const float* imb = img + (size_t)b * NBANDS * SLEN * SLEN
                               + (size_t)i4 * SLEN + col0;
        const int tot = nj * 200;   // within-chunk w == jj*200 + c*100 + rr*5 + q

        for (int w = tid; w < tot; w += 256) {
            int jj  = w / 200;
            int rem = w - jj * 200;
            int c   = rem / 100;
            int r2  = rem - c * 100;
            int rr  = r2 / 5;
            int q   = r2 - rr * 5;
            const vf4 v = *reinterpret_cast<const vf4*>(
                imb + ((size_t)(c * SLEN + rr)) * SLEN + jj * 4 + q * 4);
            dst[w] = v;
        }
    } else {
        // ---------------- per-tile catalog ----------------
        const int sub = (bid - TILE_BLOCKS) * 256 + tid;
        if (sub >= NSUB) return;

        const int b = sub / NPT;
        const int t = sub % NPT;
        const int i = t / N1;
        const int j = t % N1;

        const float lox = (float)(i * STEP) + 1.5f;   // tc.x + EP - 0.5
        const float loy = (float)(j * STEP) + 1.5f;
        const float hix = lox + 16.0f;                // tc - 0.5 + PT - EP
        const float hiy = loy + 16.0f;

        int   cnt = 0;
        int   sid[2] = {0, 0};
        float slx[2] = {0.f, 0.f};
        float sly[2] = {0.f, 0.f};

        const float* lb = locs + (size_t)b * NS * 2;
        #pragma unroll
        for (int s = 0; s < NS; ++s) {
            float lx = lb[2 * s + 0] * (float)(SLEN - 1);
            float ly = lb[2 * s + 1] * (float)(SLEN - 1);
            bool on = (lx > lox) && (lx < hix) && (ly > loy) && (ly < hiy);
            if (on) {
                if (cnt < MAXD) { sid[cnt] = s; slx[cnt] = lx; sly[cnt] = ly; }
                cnt++;
            }
        }

        const float inv_scale = 1.0f / 16.0f;  // 1/(PT-2*EP), exact

        float4 lv;
        lv.x = (cnt > 0) ? fmaxf((slx[0] - lox) * inv_scale, 0.0f) : 0.0f;
        lv.y = (cnt > 0) ? fmaxf((sly[0] - loy) * inv_scale, 0.0f) : 0.0f;
        lv.z = (cnt > 1) ? fmaxf((slx[1] - lox) * inv_scale, 0.0f) : 0.0f;
        lv.w = (cnt > 1) ? fmaxf((sly[1] - loy) * inv_scale, 0.0f) : 0.0f;
        reinterpret_cast<float4*>(out + OFF_LOCS)[sub] = lv;

        float4 g0 = {0,0,0,0}, g1 = {0,0,0,0}, g2 = {0,0,0,0}, g3 = {0,0,0,0};
        if (cnt > 0) {
            const float4* gp = reinterpret_cast<const float4*>(
                gal + ((size_t)(b * NS + sid[0])) * NGAL);
            g0 = gp[0]; g1 = gp[1];
        }
        if (cnt > 1) {
            const float4* gp = reinterpret_cast<const float4*>(
                gal + ((size_t)(b * NS + sid[1])) * NGAL);
            g2 = gp[0]; g3 = gp[1];
        }
        float4* go = reinterpret_cast<float4*>(out + OFF_GAL) + (size_t)sub * 4;
        go[0] = g0; go[1] = g1; go[2] = g2; go[3] = g3;

        float4 fv = {0,0,0,0};
        if (cnt > 0) {
            const float2 f = reinterpret_cast<const float2*>(
                flux + ((size_t)(b * NS + sid[0])) * NBANDS)[0];
            fv.x = f.x; fv.y = f.y;
        }
        if (cnt > 1) {
            const float2 f = reinterpret_cast<const float2*>(
                flux + ((size_t)(b * NS + sid[1])) * NBANDS)[0];
            fv.z = f.x; fv.w = f.y;
        }
        reinterpret_cast<float4*>(out + OFF_FLUX)[sub] = fv;

        out[OFF_N + sub] = (float)(cnt < MAXD ? cnt : MAXD);
        float2 ison;
        ison.x = (cnt > 0) ? 1.0f : 0.0f;
        ison.y = (cnt > 1) ? 1.0f : 0.0f;
        reinterpret_cast<float2*>(out + OFF_ISON)[sub] = ison;
    }
}

extern "C" void kernel_launch(void* const* d_in, const int* in_sizes, int n_in,
                              void* d_out, int out_size, void* d_ws, size_t ws_size,
                              hipStream_t stream)
{
    const float* images = (const float*)d_in[0];
    const float* locs   = (const float*)d_in[1];
    const float* gal    = (const float*)d_in[2];
    const float* flux   = (const float*)d_in[3];
    float* out = (float*)d_out;

    fused_kernel<<<TILE_BLOCKS + CAT_BLOCKS, 256, 0, stream>>>(
        images, locs, gal, flux, out);
}

// Round 5
// 28.177 us; speedup vs baseline: 1.3053x; 1.0644x over previous
//
#include <hip/hip_runtime.h>

#define SLEN   300
#define PT     20
#define STEP   4
#define MAXD   2
#define NBANDS 2
#define NS     30
#define NGAL   8
#define BATCH  8
#define N1     71            // (300-20)/4+1
#define NPT    (N1*N1)       // 5041
#define NSUB   (BATCH*NPT)   // 40328

// ---- output layout (flat float32, in reference return order) ----
#define OFF_LOCS 32262400
#define OFF_GAL  32423712
#define OFF_FLUX 33068960
#define OFF_N    33230272
#define OFF_ISON 33270600

// tiling decomposition: one block per (batch, patch-row i, j-quarter)
#define JQ   4
#define NJQ  18                               // j's per quarter (last has 17)
#define TILE_BLOCKS (BATCH * N1 * JQ)         // 2272 = 8 * 284
#define CAT_BLOCKS  ((NSUB + 255) / 256)      // 158
#define CHUNK (TILE_BLOCKS / 8)               // 284 blocks per XCD

typedef float vf4 __attribute__((ext_vector_type(4)));

// XCD-aware swizzle: hardware round-robins blockIdx across the 8 XCDs, so
// wg = (bid&7)*284 + (bid>>3) gives XCD k the contiguous chunk [k*284,(k+1)*284)
// == batch b=k, i=0..70 — per-XCD image footprint 720 KB (fits 4 MiB L2)
// instead of the whole 5.76 MB image.
__global__ __launch_bounds__(256) void fused_kernel(
    const float* __restrict__ img,
    const float* __restrict__ locs,
    const float* __restrict__ gal,
    const float* __restrict__ flux,
    float* __restrict__ out)
{
    const int bid = blockIdx.x;
    const int tid = threadIdx.x;

    if (bid < TILE_BLOCKS) {
        // ---------------- patch extraction (direct L1/L2-cached reads) -----
        const int wg = (bid & 7) * CHUNK + (bid >> 3);   // bijective XCD swizzle
        const int jq = wg & 3;
        const int bi = wg >> 2;
        const int i  = bi % N1;
        const int b  = bi / N1;
        const int j0 = jq * NJQ;
        const int nj = (jq == 3) ? (N1 - 3 * NJQ) : NJQ;   // 17 or 18
        const int col0 = j0 * STEP;
        const int i4   = i * STEP;

        const int sub0 = b * NPT + i * N1 + j0;
        vf4* dst = reinterpret_cast<vf4*>(out) + (size_t)sub0 * 200;
        const float* imb = img + (size_t)b * NBANDS * SLEN * SLEN
                               + (size_t)i4 * SLEN + col0;
        const int tot = nj * 200;   // within-chunk w == jj*200 + c*100 + rr*5 + q

        for (int w = tid; w < tot; w += 256) {
            int jj  = w / 200;
            int rem = w - jj * 200;
            int c   = rem / 100;
            int r2  = rem - c * 100;
            int rr  = r2 / 5;
            int q   = r2 - rr * 5;
            const vf4 v = *reinterpret_cast<const vf4*>(
                imb + ((size_t)(c * SLEN + rr)) * SLEN + jj * 4 + q * 4);
            dst[w] = v;
        }
    } else {
        // ---------------- per-tile catalog ----------------
        const int sub = (bid - TILE_BLOCKS) * 256 + tid;
        if (sub >= NSUB) return;

        const int b = sub / NPT;
        const int t = sub % NPT;
        const int i = t / N1;
        const int j = t % N1;

        const float lox = (float)(i * STEP) + 1.5f;   // tc.x + EP - 0.5
        const float loy = (float)(j * STEP) + 1.5f;
        const float hix = lox + 16.0f;                // tc - 0.5 + PT - EP
        const float hiy = loy + 16.0f;

        int   cnt = 0;
        int   sid[2] = {0, 0};
        float slx[2] = {0.f, 0.f};
        float sly[2] = {0.f, 0.f};

        const float* lb = locs + (size_t)b * NS * 2;
        #pragma unroll
        for (int s = 0; s < NS; ++s) {
            float lx = lb[2 * s + 0] * (float)(SLEN - 1);
            float ly = lb[2 * s + 1] * (float)(SLEN - 1);
            bool on = (lx > lox) && (lx < hix) && (ly > loy) && (ly < hiy);
            if (on) {
                if (cnt < MAXD) { sid[cnt] = s; slx[cnt] = lx; sly[cnt] = ly; }
                cnt++;
            }
        }

        const float inv_scale = 1.0f / 16.0f;  // 1/(PT-2*EP), exact

        float4 lv;
        lv.x = (cnt > 0) ? fmaxf((slx[0] - lox) * inv_scale, 0.0f) : 0.0f;
        lv.y = (cnt > 0) ? fmaxf((sly[0] - loy) * inv_scale, 0.0f) : 0.0f;
        lv.z = (cnt > 1) ? fmaxf((slx[1] - lox) * inv_scale, 0.0f) : 0.0f;
        lv.w = (cnt > 1) ? fmaxf((sly[1] - loy) * inv_scale, 0.0f) : 0.0f;
        reinterpret_cast<float4*>(out + OFF_LOCS)[sub] = lv;

        float4 g0 = {0,0,0,0}, g1 = {0,0,0,0}, g2 = {0,0,0,0}, g3 = {0,0,0,0};
        if (cnt > 0) {
            const float4* gp = reinterpret_cast<const float4*>(
                gal + ((size_t)(b * NS + sid[0])) * NGAL);
            g0 = gp[0]; g1 = gp[1];
        }
        if (cnt > 1) {
            const float4* gp = reinterpret_cast<const float4*>(
                gal + ((size_t)(b * NS + sid[1])) * NGAL);
            g2 = gp[0]; g3 = gp[1];
        }
        float4* go = reinterpret_cast<float4*>(out + OFF_GAL) + (size_t)sub * 4;
        go[0] = g0; go[1] = g1; go[2] = g2; go[3] = g3;

        float4 fv = {0,0,0,0};
        if (cnt > 0) {
            const float2 f = reinterpret_cast<const float2*>(
                flux + ((size_t)(b * NS + sid[0])) * NBANDS)[0];
            fv.x = f.x; fv.y = f.y;
        }
        if (cnt > 1) {
            const float2 f = reinterpret_cast<const float2*>(
                flux + ((size_t)(b * NS + sid[1])) * NBANDS)[0];
            fv.z = f.x; fv.w = f.y;
        }
        reinterpret_cast<float4*>(out + OFF_FLUX)[sub] = fv;

        out[OFF_N + sub] = (float)(cnt < MAXD ? cnt : MAXD);
        float2 ison;
        ison.x = (cnt > 0) ? 1.0f : 0.0f;
        ison.y = (cnt > 1) ? 1.0f : 0.0f;
        reinterpret_cast<float2*>(out + OFF_ISON)[sub] = ison;
    }
}

extern "C" void kernel_launch(void* const* d_in, const int* in_sizes, int n_in,
                              void* d_out, int out_size, void* d_ws, size_t ws_size,
                              hipStream_t stream)
{
    const float* images = (const float*)d_in[0];
    const float* locs   = (const float*)d_in[1];
    const float* gal    = (const float*)d_in[2];
    const float* flux   = (const float*)d_in[3];
    float* out = (float*)d_out;

    fused_kernel<<<TILE_BLOCKS + CAT_BLOCKS, 256, 0, stream>>>(
        images, locs, gal, flux, out);
}